// Round 9
// baseline (996.473 us; speedup 1.0000x reference)
//
#include <hip/hip_runtime.h>

#define N_NODES 50000
#define E_EDGES 800000
#define R_REL 3
#define HID 128
#define HEADS 4
#define CAP 64               // per-(relation,node) slot capacity; P(indeg>63) ~ 1e-19
#define NPART 8              // dst partitions per relation (exclusive block ownership)
#define PSIZE 6250           // 50000/8 nodes per partition

typedef __attribute__((ext_vector_type(8))) short short8;   // 8 bf16 in 4 VGPRs
typedef __attribute__((ext_vector_type(4))) float float4v;  // MFMA C/D frag

__device__ __forceinline__ unsigned short f2bf(float f) {
    unsigned int u = __float_as_uint(f);
    u += 0x7fffu + ((u >> 16) & 1u);     // round-to-nearest-even
    return (unsigned short)(u >> 16);
}
__device__ __forceinline__ float bf_lo(unsigned int u) { return __uint_as_float(u << 16); }
__device__ __forceinline__ float bf_hi(unsigned int u) { return __uint_as_float(u & 0xffff0000u); }

// ---------------- small setup: W -> W^T bf16, gw softmax (cnt zeroing no longer needed) ----------------
#define WCONV_T (R_REL * HID * HID)          // 49152
__global__ __launch_bounds__(256) void setup_kernel(const float* __restrict__ W,
                                                    const float* __restrict__ gate,
                                                    unsigned short* __restrict__ wtb,
                                                    float* __restrict__ gw_out) {
    int tid = blockIdx.x * 256 + threadIdx.x;
    if (tid < WCONV_T) {
        int r = tid >> 14, rem = tid & 16383, n = rem >> 7, k = rem & 127;
        wtb[tid] = f2bf(W[r * 16384 + k * 128 + n]);   // wtb[r][n][k] = W[r][k][n]
    } else if (tid == WCONV_T) {
        float g0 = gate[0], g1 = gate[1], g2 = gate[2];
        float mg = fmaxf(g0, fmaxf(g1, g2));
        float e0 = __expf(g0 - mg), e1 = __expf(g1 - mg), e2 = __expf(g2 - mg);
        float inv = 1.f / (e0 + e1 + e2);
        gw_out[0] = e0 * inv; gw_out[1] = e1 * inv; gw_out[2] = e2 * inv;
    }
}

// ---------------- fused: atomic-free slot fill (blocks 0..23) + MFMA GEMM/alpha (rest) ----------------
// Fill: block (r,p) exclusively owns dst range [p*PSIZE,(p+1)*PSIZE); streams the whole
//       relation-r edge list (coalesced int4), positions via LDS atomics, slots slice stays
//       L2-resident -> dense writeback; exact counts stored wholesale. ZERO global atomics.
// GEMM: A = W^T (rows=channels), B = x^T in-register bf16 -> D[channel reg][node lane].
#define FILL_BLKS (R_REL * NPART)             // 24
#define STRIPS 3125
#define BLK_PER_REL 782                       // ceil(3125/4)
#define GEMM_BLKS (R_REL * BLK_PER_REL)       // 2346
__global__ __launch_bounds__(256) void gemm_fill_kernel(const float* __restrict__ x,
                                                        const unsigned short* __restrict__ wtb,
                                                        unsigned short* __restrict__ hb,
                                                        const float* __restrict__ att_src,
                                                        const float* __restrict__ att_dst,
                                                        float* __restrict__ asrc,
                                                        float* __restrict__ adst,
                                                        const int* __restrict__ edge_idx,
                                                        int* __restrict__ cnt,
                                                        unsigned short* __restrict__ slots) {
    __shared__ int lc[PSIZE];                 // 25 KB; only used by fill blocks
    int bid = blockIdx.x;
    if (bid < FILL_BLKS) {
        int r = bid / NPART;
        int p = bid - r * NPART;
        int base = p * PSIZE;
        for (int i = threadIdx.x; i < PSIZE; i += 256) lc[i] = 0;
        __syncthreads();
        const int4* s4 = (const int4*)(edge_idx + (long)r * 2 * E_EDGES);
        const int4* d4 = (const int4*)(edge_idx + (long)r * 2 * E_EDGES + E_EDGES);
        for (int i = threadIdx.x; i < E_EDGES / 4; i += 256) {
            int4 dv = d4[i];
            int4 sv = s4[i];
#pragma unroll
            for (int j = 0; j < 4; ++j) {
                int dst = (j == 0) ? dv.x : (j == 1) ? dv.y : (j == 2) ? dv.z : dv.w;
                unsigned rel = (unsigned)(dst - base);
                if (rel < PSIZE) {
                    int src = (j == 0) ? sv.x : (j == 1) ? sv.y : (j == 2) ? sv.z : sv.w;
                    int pos = atomicAdd(&lc[rel], 1);   // LDS atomic — workgroup scope
                    if (pos < CAP)
                        slots[((long)r * N_NODES + dst) * CAP + pos] = (unsigned short)src;
                }
            }
        }
        __syncthreads();
        for (int i = threadIdx.x; i < PSIZE; i += 256)
            cnt[r * N_NODES + base + i] = lc[i];
        return;
    }
    int gb = bid - FILL_BLKS;
    int r = gb / BLK_PER_REL;
    int sb = gb % BLK_PER_REL;
    int strip = sb * 4 + (threadIdx.x >> 6);
    if (strip >= STRIPS) return;
    int lane = threadIdx.x & 63;
    int m = lane & 15, quad = lane >> 4;

    // B-operand: lane m reads fp32 row strip*16+m, k-chunk quad*8, converts to bf16 in-register
    const float* xrow = x + (long)(strip * 16 + m) * HID + quad * 8;
    short8 B[4];
#pragma unroll
    for (int kc = 0; kc < 4; ++kc) {
        float4 f0 = *(const float4*)(xrow + kc * 32);
        float4 f1 = *(const float4*)(xrow + kc * 32 + 4);
        short8 b;
        b[0] = (short)f2bf(f0.x); b[1] = (short)f2bf(f0.y);
        b[2] = (short)f2bf(f0.z); b[3] = (short)f2bf(f0.w);
        b[4] = (short)f2bf(f1.x); b[5] = (short)f2bf(f1.y);
        b[6] = (short)f2bf(f1.z); b[7] = (short)f2bf(f1.w);
        B[kc] = b;
    }

    const unsigned short* wt = wtb + r * HID * HID;
    float4v acc[8];
#pragma unroll
    for (int cb = 0; cb < 8; ++cb) acc[cb] = (float4v){0.f, 0.f, 0.f, 0.f};
#pragma unroll
    for (int cb = 0; cb < 8; ++cb) {
        const unsigned short* wrow = wt + (cb * 16 + m) * HID + quad * 8;
#pragma unroll
        for (int kc = 0; kc < 4; ++kc) {
            short8 A = *(const short8*)(wrow + kc * 32);
            acc[cb] = __builtin_amdgcn_mfma_f32_16x16x32_bf16(A, B[kc], acc[cb], 0, 0, 0);
        }
    }
    int node = strip * 16 + m;
    // packed bf16 store: 8 x uint2 per lane, channels cb*16+quad*4+{0..3} of this lane's node
    unsigned short* hrow = hb + ((long)r * N_NODES + node) * HID;
#pragma unroll
    for (int cb = 0; cb < 8; ++cb) {
        uint2 o;
        o.x = f2bf(acc[cb][0]) | ((unsigned)f2bf(acc[cb][1]) << 16);
        o.y = f2bf(acc[cb][2]) | ((unsigned)f2bf(acc[cb][3]) << 16);
        *(uint2*)(hrow + cb * 16 + quad * 4) = o;
    }
    // alpha epilogue: per-head dots with att vectors from fp32 acc, reduce across quads
    const float* ar = att_src + r * HID;
    const float* dr = att_dst + r * HID;
    float sa[4] = {0.f, 0.f, 0.f, 0.f}, sd[4] = {0.f, 0.f, 0.f, 0.f};
#pragma unroll
    for (int cb = 0; cb < 8; ++cb) {
        int hd = cb >> 1;
#pragma unroll
        for (int i = 0; i < 4; ++i) {
            int c = cb * 16 + quad * 4 + i;
            sa[hd] += acc[cb][i] * ar[c];
            sd[hd] += acc[cb][i] * dr[c];
        }
    }
#pragma unroll
    for (int hd = 0; hd < 4; ++hd) {
        sa[hd] += __shfl_xor(sa[hd], 16, 64); sa[hd] += __shfl_xor(sa[hd], 32, 64);
        sd[hd] += __shfl_xor(sd[hd], 16, 64); sd[hd] += __shfl_xor(sd[hd], 32, 64);
    }
    // quad q writes head q: 64 lanes -> 64 consecutive dwords (coalesced)
    float wa = quad == 0 ? sa[0] : quad == 1 ? sa[1] : quad == 2 ? sa[2] : sa[3];
    float wd = quad == 0 ? sd[0] : quad == 1 ? sd[1] : quad == 2 ? sd[2] : sd[3];
    asrc[((long)r * N_NODES + node) * 4 + quad] = wa;
    adst[((long)r * N_NODES + node) * 4 + quad] = wd;
}

// ---------------- fused gather-aggregate + gated combine + residual + LayerNorm ----------------
// One wave per dst node; quarter-waves (16 lanes) process slot entries, 2-edge unroll;
// lane owns 8 channels (l*8 .. l*8+7); ev recomputed from fp32 asrc/adst.
__global__ __launch_bounds__(256) void aggr_kernel(const unsigned short* __restrict__ hb,
                                                   const int* __restrict__ cnt,
                                                   const unsigned short* __restrict__ slots,
                                                   const float* __restrict__ asrc,
                                                   const float* __restrict__ adst,
                                                   const float* __restrict__ gate,
                                                   const float* __restrict__ x,
                                                   const float* __restrict__ bias,
                                                   const float* __restrict__ ln_g,
                                                   const float* __restrict__ ln_b,
                                                   float* __restrict__ out) {
    int node = blockIdx.x * 4 + (threadIdx.x >> 6);
    int lane = threadIdx.x & 63;
    int q = lane >> 4;                 // quarter 0..3 -> edge slot
    int l = lane & 15;                 // channel group: channels l*8 .. l*8+7
    int hd = l >> 2;                   // head of those channels
    // inline softmax(gate)
    float g0 = gate[0], g1 = gate[1], g2 = gate[2];
    float mg = fmaxf(g0, fmaxf(g1, g2));
    float e0 = __expf(g0 - mg), e1 = __expf(g1 - mg), e2 = __expf(g2 - mg);
    float ginv = 1.f / (e0 + e1 + e2);
    float gwv[R_REL] = {e0 * ginv, e1 * ginv, e2 * ginv};

    float run0 = 0.f, run1 = 0.f, run2 = 0.f, run3 = 0.f;
    float run4 = 0.f, run5 = 0.f, run6 = 0.f, run7 = 0.f;
#pragma unroll
    for (int r = 0; r < R_REL; ++r) {
        const unsigned short* hr = hb + (long)r * N_NODES * HID;
        const float* as = asrc + (long)r * N_NODES * 4;
        const float* ad = adst + (long)r * N_NODES * 4;
        int cb = r * N_NODES + node;
        int deg = cnt[cb]; deg = deg < CAP ? deg : CAP;
        const unsigned short* sl = slots + (long)cb * CAP;
        float adv = ad[node * 4 + hd];
        float a0 = 0.f, a1 = 0.f, a2 = 0.f, a3 = 0.f;
        float a4 = 0.f, a5 = 0.f, a6 = 0.f, a7 = 0.f, den = 0.f;
        int i = q;
        for (; i + 4 < deg; i += 8) {
            int src0 = sl[i];
            int src1 = sl[i + 4];
            uint4 u0 = ((const uint4*)(hr + (long)src0 * HID))[l];
            uint4 u1 = ((const uint4*)(hr + (long)src1 * HID))[l];
            float s0 = as[src0 * 4 + hd] + adv;
            s0 = s0 > 0.f ? s0 : 0.2f * s0;
            float ev0 = __expf(s0);
            float s1 = as[src1 * 4 + hd] + adv;
            s1 = s1 > 0.f ? s1 : 0.2f * s1;
            float ev1 = __expf(s1);
            a0 += ev0 * bf_lo(u0.x); a1 += ev0 * bf_hi(u0.x);
            a2 += ev0 * bf_lo(u0.y); a3 += ev0 * bf_hi(u0.y);
            a4 += ev0 * bf_lo(u0.z); a5 += ev0 * bf_hi(u0.z);
            a6 += ev0 * bf_lo(u0.w); a7 += ev0 * bf_hi(u0.w);
            a0 += ev1 * bf_lo(u1.x); a1 += ev1 * bf_hi(u1.x);
            a2 += ev1 * bf_lo(u1.y); a3 += ev1 * bf_hi(u1.y);
            a4 += ev1 * bf_lo(u1.z); a5 += ev1 * bf_hi(u1.z);
            a6 += ev1 * bf_lo(u1.w); a7 += ev1 * bf_hi(u1.w);
            den += ev0 + ev1;
        }
        if (i < deg) {
            int src = sl[i];
            uint4 u = ((const uint4*)(hr + (long)src * HID))[l];
            float s = as[src * 4 + hd] + adv;
            s = s > 0.f ? s : 0.2f * s;
            float ev = __expf(s);
            a0 += ev * bf_lo(u.x); a1 += ev * bf_hi(u.x);
            a2 += ev * bf_lo(u.y); a3 += ev * bf_hi(u.y);
            a4 += ev * bf_lo(u.z); a5 += ev * bf_hi(u.z);
            a6 += ev * bf_lo(u.w); a7 += ev * bf_hi(u.w);
            den += ev;
        }
        // merge the 4 quarters (channels identical across quarters)
        a0 += __shfl_xor(a0, 16, 64); a0 += __shfl_xor(a0, 32, 64);
        a1 += __shfl_xor(a1, 16, 64); a1 += __shfl_xor(a1, 32, 64);
        a2 += __shfl_xor(a2, 16, 64); a2 += __shfl_xor(a2, 32, 64);
        a3 += __shfl_xor(a3, 16, 64); a3 += __shfl_xor(a3, 32, 64);
        a4 += __shfl_xor(a4, 16, 64); a4 += __shfl_xor(a4, 32, 64);
        a5 += __shfl_xor(a5, 16, 64); a5 += __shfl_xor(a5, 32, 64);
        a6 += __shfl_xor(a6, 16, 64); a6 += __shfl_xor(a6, 32, 64);
        a7 += __shfl_xor(a7, 16, 64); a7 += __shfl_xor(a7, 32, 64);
        den += __shfl_xor(den, 16, 64); den += __shfl_xor(den, 32, 64);
        float inv = gwv[r] / (den + 1e-16f);
        run0 += a0 * inv; run1 += a1 * inv; run2 += a2 * inv; run3 += a3 * inv;
        run4 += a4 * inv; run5 += a5 * inv; run6 += a6 * inv; run7 += a7 * inv;
    }
    // bias mix + residual (channels l*8 .. l*8+7)
    const float4* b4 = (const float4*)bias;
    float4 b00 = b4[2 * l], b01 = b4[2 * l + 1];
    float4 b10 = b4[32 + 2 * l], b11 = b4[32 + 2 * l + 1];
    float4 b20 = b4[64 + 2 * l], b21 = b4[64 + 2 * l + 1];
    float4 xv0 = ((const float4*)x)[(long)node * 32 + 2 * l];
    float4 xv1 = ((const float4*)x)[(long)node * 32 + 2 * l + 1];
    float v0 = run0 + xv0.x + gwv[0] * b00.x + gwv[1] * b10.x + gwv[2] * b20.x;
    float v1 = run1 + xv0.y + gwv[0] * b00.y + gwv[1] * b10.y + gwv[2] * b20.y;
    float v2 = run2 + xv0.z + gwv[0] * b00.z + gwv[1] * b10.z + gwv[2] * b20.z;
    float v3 = run3 + xv0.w + gwv[0] * b00.w + gwv[1] * b10.w + gwv[2] * b20.w;
    float v4 = run4 + xv1.x + gwv[0] * b01.x + gwv[1] * b11.x + gwv[2] * b21.x;
    float v5 = run5 + xv1.y + gwv[0] * b01.y + gwv[1] * b11.y + gwv[2] * b21.y;
    float v6 = run6 + xv1.z + gwv[0] * b01.z + gwv[1] * b11.z + gwv[2] * b21.z;
    float v7 = run7 + xv1.w + gwv[0] * b01.w + gwv[1] * b11.w + gwv[2] * b21.w;
    // LayerNorm: channels duplicated 4x across quarters -> divide by 4*HID
    float sum = v0 + v1 + v2 + v3 + v4 + v5 + v6 + v7;
    float sq = v0 * v0 + v1 * v1 + v2 * v2 + v3 * v3 + v4 * v4 + v5 * v5 + v6 * v6 + v7 * v7;
#pragma unroll
    for (int off = 32; off > 0; off >>= 1) {
        sum += __shfl_xor(sum, off, 64);
        sq  += __shfl_xor(sq, off, 64);
    }
    float mean = sum * (1.f / (4 * HID));
    float var = sq * (1.f / (4 * HID)) - mean * mean;
    float rstd = rsqrtf(var + 1e-5f);
    if (q == 0) {
        float4 gv0 = ((const float4*)ln_g)[2 * l], gv1 = ((const float4*)ln_g)[2 * l + 1];
        float4 bv0 = ((const float4*)ln_b)[2 * l], bv1 = ((const float4*)ln_b)[2 * l + 1];
        float4 o0, o1;
        o0.x = (v0 - mean) * rstd * gv0.x + bv0.x;
        o0.y = (v1 - mean) * rstd * gv0.y + bv0.y;
        o0.z = (v2 - mean) * rstd * gv0.z + bv0.z;
        o0.w = (v3 - mean) * rstd * gv0.w + bv0.w;
        o1.x = (v4 - mean) * rstd * gv1.x + bv1.x;
        o1.y = (v5 - mean) * rstd * gv1.y + bv1.y;
        o1.z = (v6 - mean) * rstd * gv1.z + bv1.z;
        o1.w = (v7 - mean) * rstd * gv1.w + bv1.w;
        ((float4*)out)[(long)node * 32 + 2 * l] = o0;
        ((float4*)out)[(long)node * 32 + 2 * l + 1] = o1;
    }
}

extern "C" void kernel_launch(void* const* d_in, const int* in_sizes, int n_in,
                              void* d_out, int out_size, void* d_ws, size_t ws_size,
                              hipStream_t stream) {
    const float* x        = (const float*)d_in[0];
    const int*   edge_idx = (const int*)d_in[1];
    // d_in[2] = edge_attr, unused (GATConv built without edge_dim)
    const float* W        = (const float*)d_in[3];
    const float* att_src  = (const float*)d_in[4];
    const float* att_dst  = (const float*)d_in[5];
    const float* bias     = (const float*)d_in[6];
    const float* gate     = (const float*)d_in[7];
    const float* ln_g     = (const float*)d_in[8];
    const float* ln_b     = (const float*)d_in[9];
    float* out = (float*)d_out;

    // workspace layout (~64 MB):
    // hb[3*N*128 bf16] | asrc[3*N*4 f] | adst[3*N*4 f] | cnt[3*N int]
    // | wtb[3*128*128 bf16] | slots[3*N*64 ushort]
    unsigned short* hb  = (unsigned short*)d_ws;
    float* asrc = (float*)(hb + (long)R_REL * N_NODES * HID);
    float* adst = asrc + R_REL * N_NODES * HEADS;
    int*   cnt  = (int*)(adst + R_REL * N_NODES * HEADS);
    unsigned short* wtb = (unsigned short*)(cnt + R_REL * N_NODES);
    unsigned short* slots = wtb + R_REL * HID * HID;

    setup_kernel<<<(WCONV_T + 256) / 256, 256, 0, stream>>>(
        W, gate, wtb, out + (long)N_NODES * HID);
    gemm_fill_kernel<<<FILL_BLKS + GEMM_BLKS, 256, 0, stream>>>(
        x, wtb, hb, att_src, att_dst, asrc, adst, edge_idx, cnt, slots);
    aggr_kernel<<<N_NODES / 4, 256, 0, stream>>>(hb, cnt, slots, asrc, adst, gate,
                                                 x, bias, ln_g, ln_b, out);
}

// Round 10
// 365.617 us; speedup vs baseline: 2.7255x; 2.7255x over previous
//
#include <hip/hip_runtime.h>

#define N_NODES 50000
#define E_EDGES 800000
#define R_REL 3
#define HID 128
#define HEADS 4
#define CAP 64               // per-(relation,node) slot capacity; P(indeg>63) ~ 1e-19
#define NPART 32             // dst partitions per relation
#define PSIZE 1563           // ceil(50000/32); last partition has 1547 nodes
#define CHUNKS_A 98          // phase-A chunks per relation (98*8192 >= 800000)
#define CAP_A 448            // bucket capacity per (chunk,partition); mean 256, 12-sigma margin

typedef __attribute__((ext_vector_type(8))) short short8;   // 8 bf16 in 4 VGPRs
typedef __attribute__((ext_vector_type(4))) float float4v;  // MFMA C/D frag

__device__ __forceinline__ unsigned short f2bf(float f) {
    unsigned int u = __float_as_uint(f);
    u += 0x7fffu + ((u >> 16) & 1u);     // round-to-nearest-even
    return (unsigned short)(u >> 16);
}
__device__ __forceinline__ float bf_lo(unsigned int u) { return __uint_as_float(u << 16); }
__device__ __forceinline__ float bf_hi(unsigned int u) { return __uint_as_float(u & 0xffff0000u); }

// ---------------- dispatch 1: setup (W^T, gw) + phase-A edge bucketing ----------------
#define WCONV_T (R_REL * HID * HID)          // 49152
#define SETUP_BLKS 193                        // 192 for W^T + 1 spare thread block for gw
#define FILLA_BLKS (R_REL * CHUNKS_A)         // 294
__global__ __launch_bounds__(256) void setup_fillA_kernel(const float* __restrict__ W,
                                                          const float* __restrict__ gate,
                                                          const int* __restrict__ edge_idx,
                                                          unsigned short* __restrict__ wtb,
                                                          float* __restrict__ gw_out,
                                                          unsigned* __restrict__ regions,
                                                          int* __restrict__ bc) {
    __shared__ unsigned buf[NPART * CAP_A];   // 56 KB — only this dispatch pays it
    __shared__ int lcnt[NPART];
    int bid = blockIdx.x;
    if (bid < SETUP_BLKS) {
        int tid = bid * 256 + threadIdx.x;
        if (tid < WCONV_T) {
            int r = tid >> 14, rem = tid & 16383, n = rem >> 7, k = rem & 127;
            wtb[tid] = f2bf(W[r * 16384 + k * 128 + n]);   // wtb[r][n][k] = W[r][k][n]
        } else if (tid == WCONV_T) {
            float g0 = gate[0], g1 = gate[1], g2 = gate[2];
            float mg = fmaxf(g0, fmaxf(g1, g2));
            float e0 = __expf(g0 - mg), e1 = __expf(g1 - mg), e2 = __expf(g2 - mg);
            float inv = 1.f / (e0 + e1 + e2);
            gw_out[0] = e0 * inv; gw_out[1] = e1 * inv; gw_out[2] = e2 * inv;
        }
        return;
    }
    int fb = bid - SETUP_BLKS;
    int r = fb / CHUNKS_A, c = fb % CHUNKS_A;
    if (threadIdx.x < NPART) lcnt[threadIdx.x] = 0;
    __syncthreads();
    const int4* s4 = (const int4*)(edge_idx + (long)r * 2 * E_EDGES);
    const int4* d4 = (const int4*)(edge_idx + (long)r * 2 * E_EDGES + E_EDGES);
    int i0 = c * 2048;
    int i1 = i0 + 2048; if (i1 > E_EDGES / 4) i1 = E_EDGES / 4;
    for (int i = i0 + threadIdx.x; i < i1; i += 256) {
        int4 sv = s4[i];
        int4 dv = d4[i];
#pragma unroll
        for (int j = 0; j < 4; ++j) {
            int dst = (j == 0) ? dv.x : (j == 1) ? dv.y : (j == 2) ? dv.z : dv.w;
            int src = (j == 0) ? sv.x : (j == 1) ? sv.y : (j == 2) ? sv.z : sv.w;
            int p = dst / PSIZE;
            int reldst = dst - p * PSIZE;
            int pos = atomicAdd(&lcnt[p], 1);
            if (pos < CAP_A) buf[p * CAP_A + pos] = ((unsigned)reldst << 16) | (unsigned)src;
        }
    }
    __syncthreads();
    long rbase = (long)(r * CHUNKS_A + c) * NPART;
#pragma unroll 4
    for (int p = 0; p < NPART; ++p) {
        int n = lcnt[p]; if (n > CAP_A) n = CAP_A;
        unsigned* dp = regions + (rbase + p) * CAP_A;
        for (int i = threadIdx.x; i < n; i += 256) dp[i] = buf[p * CAP_A + i];
    }
    if (threadIdx.x < NPART) {
        int n = lcnt[threadIdx.x]; if (n > CAP_A) n = CAP_A;
        bc[rbase + threadIdx.x] = n;
    }
}

// ---------------- dispatch 2: phase-B slot build (blocks 0..95) + MFMA GEMM/alpha (rest) ----------------
// FillB: block (r,p) exclusively owns dst range [p*PSIZE, ...); drains its 98 bucket lists
//        (coalesced), positions via LDS atomics, slot slice (600 KB) stays L2-dense.
// GEMM:  A = W^T (rows=channels), B = x^T in-register bf16 -> D[channel reg][node lane].
#define FILLB_BLKS (R_REL * NPART)            // 96
#define STRIPS 3125
#define BLK_PER_REL 782                       // ceil(3125/4)
#define GEMM_BLKS (R_REL * BLK_PER_REL)       // 2346
__global__ __launch_bounds__(256) void gemm_fillB_kernel(const float* __restrict__ x,
                                                         const unsigned short* __restrict__ wtb,
                                                         unsigned short* __restrict__ hb,
                                                         const float* __restrict__ att_src,
                                                         const float* __restrict__ att_dst,
                                                         float* __restrict__ asrc,
                                                         float* __restrict__ adst,
                                                         const unsigned* __restrict__ regions,
                                                         const int* __restrict__ bc,
                                                         int* __restrict__ cnt,
                                                         unsigned short* __restrict__ slots) {
    __shared__ int lc[PSIZE];                 // 6.25 KB — does not bind gemm occupancy
    int bid = blockIdx.x;
    if (bid < FILLB_BLKS) {
        int r = bid / NPART, p = bid % NPART;
        int base = p * PSIZE;
        int psz = N_NODES - base; if (psz > PSIZE) psz = PSIZE;
        for (int i = threadIdx.x; i < PSIZE; i += 256) lc[i] = 0;
        __syncthreads();
        for (int c = 0; c < CHUNKS_A; ++c) {
            long rb = (long)(r * CHUNKS_A + c) * NPART + p;
            int n = bc[rb];
            const unsigned* sp = regions + rb * CAP_A;
            for (int i = threadIdx.x; i < n; i += 256) {
                unsigned e = sp[i];
                int reldst = e >> 16;
                int src = e & 0xffff;
                int pos = atomicAdd(&lc[reldst], 1);   // LDS atomic — workgroup scope
                if (pos < CAP)
                    slots[((long)(r * N_NODES + base + reldst)) * CAP + pos] = (unsigned short)src;
            }
        }
        __syncthreads();
        for (int i = threadIdx.x; i < psz; i += 256)
            cnt[r * N_NODES + base + i] = lc[i];
        return;
    }
    int gb = bid - FILLB_BLKS;
    int r = gb / BLK_PER_REL;
    int sb = gb % BLK_PER_REL;
    int strip = sb * 4 + (threadIdx.x >> 6);
    if (strip >= STRIPS) return;
    int lane = threadIdx.x & 63;
    int m = lane & 15, quad = lane >> 4;

    // B-operand: lane m reads fp32 row strip*16+m, k-chunk quad*8, converts to bf16 in-register
    const float* xrow = x + (long)(strip * 16 + m) * HID + quad * 8;
    short8 B[4];
#pragma unroll
    for (int kc = 0; kc < 4; ++kc) {
        float4 f0 = *(const float4*)(xrow + kc * 32);
        float4 f1 = *(const float4*)(xrow + kc * 32 + 4);
        short8 b;
        b[0] = (short)f2bf(f0.x); b[1] = (short)f2bf(f0.y);
        b[2] = (short)f2bf(f0.z); b[3] = (short)f2bf(f0.w);
        b[4] = (short)f2bf(f1.x); b[5] = (short)f2bf(f1.y);
        b[6] = (short)f2bf(f1.z); b[7] = (short)f2bf(f1.w);
        B[kc] = b;
    }

    const unsigned short* wt = wtb + r * HID * HID;
    float4v acc[8];
#pragma unroll
    for (int cb = 0; cb < 8; ++cb) acc[cb] = (float4v){0.f, 0.f, 0.f, 0.f};
#pragma unroll
    for (int cb = 0; cb < 8; ++cb) {
        const unsigned short* wrow = wt + (cb * 16 + m) * HID + quad * 8;
#pragma unroll
        for (int kc = 0; kc < 4; ++kc) {
            short8 A = *(const short8*)(wrow + kc * 32);
            acc[cb] = __builtin_amdgcn_mfma_f32_16x16x32_bf16(A, B[kc], acc[cb], 0, 0, 0);
        }
    }
    int node = strip * 16 + m;
    // packed bf16 store: 8 x uint2 per lane, channels cb*16+quad*4+{0..3} of this lane's node
    unsigned short* hrow = hb + ((long)r * N_NODES + node) * HID;
#pragma unroll
    for (int cb = 0; cb < 8; ++cb) {
        uint2 o;
        o.x = f2bf(acc[cb][0]) | ((unsigned)f2bf(acc[cb][1]) << 16);
        o.y = f2bf(acc[cb][2]) | ((unsigned)f2bf(acc[cb][3]) << 16);
        *(uint2*)(hrow + cb * 16 + quad * 4) = o;
    }
    // alpha epilogue: per-head dots with att vectors from fp32 acc, reduce across quads
    const float* ar = att_src + r * HID;
    const float* dr = att_dst + r * HID;
    float sa[4] = {0.f, 0.f, 0.f, 0.f}, sd[4] = {0.f, 0.f, 0.f, 0.f};
#pragma unroll
    for (int cb = 0; cb < 8; ++cb) {
        int hd = cb >> 1;
#pragma unroll
        for (int i = 0; i < 4; ++i) {
            int c = cb * 16 + quad * 4 + i;
            sa[hd] += acc[cb][i] * ar[c];
            sd[hd] += acc[cb][i] * dr[c];
        }
    }
#pragma unroll
    for (int hd = 0; hd < 4; ++hd) {
        sa[hd] += __shfl_xor(sa[hd], 16, 64); sa[hd] += __shfl_xor(sa[hd], 32, 64);
        sd[hd] += __shfl_xor(sd[hd], 16, 64); sd[hd] += __shfl_xor(sd[hd], 32, 64);
    }
    // quad q writes head q: 64 lanes -> 64 consecutive dwords (coalesced)
    float wa = quad == 0 ? sa[0] : quad == 1 ? sa[1] : quad == 2 ? sa[2] : sa[3];
    float wd = quad == 0 ? sd[0] : quad == 1 ? sd[1] : quad == 2 ? sd[2] : sd[3];
    asrc[((long)r * N_NODES + node) * 4 + quad] = wa;
    adst[((long)r * N_NODES + node) * 4 + quad] = wd;
}

// ---------------- fused gather-aggregate + gated combine + residual + LayerNorm ----------------
// One wave per dst node; quarter-waves (16 lanes) process slot entries, 4-edge unroll;
// lane owns 8 channels (l*8 .. l*8+7); ev recomputed from fp32 asrc/adst.
__global__ __launch_bounds__(256) void aggr_kernel(const unsigned short* __restrict__ hb,
                                                   const int* __restrict__ cnt,
                                                   const unsigned short* __restrict__ slots,
                                                   const float* __restrict__ asrc,
                                                   const float* __restrict__ adst,
                                                   const float* __restrict__ gate,
                                                   const float* __restrict__ x,
                                                   const float* __restrict__ bias,
                                                   const float* __restrict__ ln_g,
                                                   const float* __restrict__ ln_b,
                                                   float* __restrict__ out) {
    int node = blockIdx.x * 4 + (threadIdx.x >> 6);
    int lane = threadIdx.x & 63;
    int q = lane >> 4;                 // quarter 0..3 -> edge slot
    int l = lane & 15;                 // channel group: channels l*8 .. l*8+7
    int hd = l >> 2;                   // head of those channels
    // inline softmax(gate)
    float g0 = gate[0], g1 = gate[1], g2 = gate[2];
    float mg = fmaxf(g0, fmaxf(g1, g2));
    float e0 = __expf(g0 - mg), e1 = __expf(g1 - mg), e2 = __expf(g2 - mg);
    float ginv = 1.f / (e0 + e1 + e2);
    float gwv[R_REL] = {e0 * ginv, e1 * ginv, e2 * ginv};

    float run0 = 0.f, run1 = 0.f, run2 = 0.f, run3 = 0.f;
    float run4 = 0.f, run5 = 0.f, run6 = 0.f, run7 = 0.f;
#pragma unroll
    for (int r = 0; r < R_REL; ++r) {
        const unsigned short* hr = hb + (long)r * N_NODES * HID;
        const float* as = asrc + (long)r * N_NODES * 4;
        const float* ad = adst + (long)r * N_NODES * 4;
        int cb = r * N_NODES + node;
        int deg = cnt[cb]; deg = deg < CAP ? deg : CAP;
        const unsigned short* sl = slots + (long)cb * CAP;
        float adv = ad[node * 4 + hd];
        float a0 = 0.f, a1 = 0.f, a2 = 0.f, a3 = 0.f;
        float a4 = 0.f, a5 = 0.f, a6 = 0.f, a7 = 0.f, den = 0.f;
        int i = q;
        for (; i + 12 < deg; i += 16) {      // 4 edges in flight per quarter
            int s0i = sl[i], s1i = sl[i + 4], s2i = sl[i + 8], s3i = sl[i + 12];
            uint4 u0 = ((const uint4*)(hr + (long)s0i * HID))[l];
            uint4 u1 = ((const uint4*)(hr + (long)s1i * HID))[l];
            uint4 u2 = ((const uint4*)(hr + (long)s2i * HID))[l];
            uint4 u3 = ((const uint4*)(hr + (long)s3i * HID))[l];
            float t0 = as[s0i * 4 + hd] + adv; t0 = t0 > 0.f ? t0 : 0.2f * t0;
            float t1 = as[s1i * 4 + hd] + adv; t1 = t1 > 0.f ? t1 : 0.2f * t1;
            float t2 = as[s2i * 4 + hd] + adv; t2 = t2 > 0.f ? t2 : 0.2f * t2;
            float t3 = as[s3i * 4 + hd] + adv; t3 = t3 > 0.f ? t3 : 0.2f * t3;
            float ev0 = __expf(t0), ev1 = __expf(t1), ev2 = __expf(t2), ev3 = __expf(t3);
            a0 += ev0 * bf_lo(u0.x); a1 += ev0 * bf_hi(u0.x);
            a2 += ev0 * bf_lo(u0.y); a3 += ev0 * bf_hi(u0.y);
            a4 += ev0 * bf_lo(u0.z); a5 += ev0 * bf_hi(u0.z);
            a6 += ev0 * bf_lo(u0.w); a7 += ev0 * bf_hi(u0.w);
            a0 += ev1 * bf_lo(u1.x); a1 += ev1 * bf_hi(u1.x);
            a2 += ev1 * bf_lo(u1.y); a3 += ev1 * bf_hi(u1.y);
            a4 += ev1 * bf_lo(u1.z); a5 += ev1 * bf_hi(u1.z);
            a6 += ev1 * bf_lo(u1.w); a7 += ev1 * bf_hi(u1.w);
            a0 += ev2 * bf_lo(u2.x); a1 += ev2 * bf_hi(u2.x);
            a2 += ev2 * bf_lo(u2.y); a3 += ev2 * bf_hi(u2.y);
            a4 += ev2 * bf_lo(u2.z); a5 += ev2 * bf_hi(u2.z);
            a6 += ev2 * bf_lo(u2.w); a7 += ev2 * bf_hi(u2.w);
            a0 += ev3 * bf_lo(u3.x); a1 += ev3 * bf_hi(u3.x);
            a2 += ev3 * bf_lo(u3.y); a3 += ev3 * bf_hi(u3.y);
            a4 += ev3 * bf_lo(u3.z); a5 += ev3 * bf_hi(u3.z);
            a6 += ev3 * bf_lo(u3.w); a7 += ev3 * bf_hi(u3.w);
            den += (ev0 + ev1) + (ev2 + ev3);
        }
        for (; i < deg; i += 4) {
            int src = sl[i];
            uint4 u = ((const uint4*)(hr + (long)src * HID))[l];
            float s = as[src * 4 + hd] + adv;
            s = s > 0.f ? s : 0.2f * s;
            float ev = __expf(s);
            a0 += ev * bf_lo(u.x); a1 += ev * bf_hi(u.x);
            a2 += ev * bf_lo(u.y); a3 += ev * bf_hi(u.y);
            a4 += ev * bf_lo(u.z); a5 += ev * bf_hi(u.z);
            a6 += ev * bf_lo(u.w); a7 += ev * bf_hi(u.w);
            den += ev;
        }
        // merge the 4 quarters (channels identical across quarters)
        a0 += __shfl_xor(a0, 16, 64); a0 += __shfl_xor(a0, 32, 64);
        a1 += __shfl_xor(a1, 16, 64); a1 += __shfl_xor(a1, 32, 64);
        a2 += __shfl_xor(a2, 16, 64); a2 += __shfl_xor(a2, 32, 64);
        a3 += __shfl_xor(a3, 16, 64); a3 += __shfl_xor(a3, 32, 64);
        a4 += __shfl_xor(a4, 16, 64); a4 += __shfl_xor(a4, 32, 64);
        a5 += __shfl_xor(a5, 16, 64); a5 += __shfl_xor(a5, 32, 64);
        a6 += __shfl_xor(a6, 16, 64); a6 += __shfl_xor(a6, 32, 64);
        a7 += __shfl_xor(a7, 16, 64); a7 += __shfl_xor(a7, 32, 64);
        den += __shfl_xor(den, 16, 64); den += __shfl_xor(den, 32, 64);
        float inv = gwv[r] / (den + 1e-16f);
        run0 += a0 * inv; run1 += a1 * inv; run2 += a2 * inv; run3 += a3 * inv;
        run4 += a4 * inv; run5 += a5 * inv; run6 += a6 * inv; run7 += a7 * inv;
    }
    // bias mix + residual (channels l*8 .. l*8+7)
    const float4* b4 = (const float4*)bias;
    float4 b00 = b4[2 * l], b01 = b4[2 * l + 1];
    float4 b10 = b4[32 + 2 * l], b11 = b4[32 + 2 * l + 1];
    float4 b20 = b4[64 + 2 * l], b21 = b4[64 + 2 * l + 1];
    float4 xv0 = ((const float4*)x)[(long)node * 32 + 2 * l];
    float4 xv1 = ((const float4*)x)[(long)node * 32 + 2 * l + 1];
    float v0 = run0 + xv0.x + gwv[0] * b00.x + gwv[1] * b10.x + gwv[2] * b20.x;
    float v1 = run1 + xv0.y + gwv[0] * b00.y + gwv[1] * b10.y + gwv[2] * b20.y;
    float v2 = run2 + xv0.z + gwv[0] * b00.z + gwv[1] * b10.z + gwv[2] * b20.z;
    float v3 = run3 + xv0.w + gwv[0] * b00.w + gwv[1] * b10.w + gwv[2] * b20.w;
    float v4 = run4 + xv1.x + gwv[0] * b01.x + gwv[1] * b11.x + gwv[2] * b21.x;
    float v5 = run5 + xv1.y + gwv[0] * b01.y + gwv[1] * b11.y + gwv[2] * b21.y;
    float v6 = run6 + xv1.z + gwv[0] * b01.z + gwv[1] * b11.z + gwv[2] * b21.z;
    float v7 = run7 + xv1.w + gwv[0] * b01.w + gwv[1] * b11.w + gwv[2] * b21.w;
    // LayerNorm: channels duplicated 4x across quarters -> divide by 4*HID
    float sum = v0 + v1 + v2 + v3 + v4 + v5 + v6 + v7;
    float sq = v0 * v0 + v1 * v1 + v2 * v2 + v3 * v3 + v4 * v4 + v5 * v5 + v6 * v6 + v7 * v7;
#pragma unroll
    for (int off = 32; off > 0; off >>= 1) {
        sum += __shfl_xor(sum, off, 64);
        sq  += __shfl_xor(sq, off, 64);
    }
    float mean = sum * (1.f / (4 * HID));
    float var = sq * (1.f / (4 * HID)) - mean * mean;
    float rstd = rsqrtf(var + 1e-5f);
    if (q == 0) {
        float4 gv0 = ((const float4*)ln_g)[2 * l], gv1 = ((const float4*)ln_g)[2 * l + 1];
        float4 bv0 = ((const float4*)ln_b)[2 * l], bv1 = ((const float4*)ln_b)[2 * l + 1];
        float4 o0, o1;
        o0.x = (v0 - mean) * rstd * gv0.x + bv0.x;
        o0.y = (v1 - mean) * rstd * gv0.y + bv0.y;
        o0.z = (v2 - mean) * rstd * gv0.z + bv0.z;
        o0.w = (v3 - mean) * rstd * gv0.w + bv0.w;
        o1.x = (v4 - mean) * rstd * gv1.x + bv1.x;
        o1.y = (v5 - mean) * rstd * gv1.y + bv1.y;
        o1.z = (v6 - mean) * rstd * gv1.z + bv1.z;
        o1.w = (v7 - mean) * rstd * gv1.w + bv1.w;
        ((float4*)out)[(long)node * 32 + 2 * l] = o0;
        ((float4*)out)[(long)node * 32 + 2 * l + 1] = o1;
    }
}

extern "C" void kernel_launch(void* const* d_in, const int* in_sizes, int n_in,
                              void* d_out, int out_size, void* d_ws, size_t ws_size,
                              hipStream_t stream) {
    const float* x        = (const float*)d_in[0];
    const int*   edge_idx = (const int*)d_in[1];
    // d_in[2] = edge_attr, unused (GATConv built without edge_dim)
    const float* W        = (const float*)d_in[3];
    const float* att_src  = (const float*)d_in[4];
    const float* att_dst  = (const float*)d_in[5];
    const float* bias     = (const float*)d_in[6];
    const float* gate     = (const float*)d_in[7];
    const float* ln_g     = (const float*)d_in[8];
    const float* ln_b     = (const float*)d_in[9];
    float* out = (float*)d_out;

    // workspace layout (~81 MB):
    // hb[3*N*128 bf16] | asrc[3*N*4 f] | adst[3*N*4 f] | cnt[3*N int]
    // | wtb[3*128*128 bf16] | slots[3*N*64 ushort] | regions[3*98*32*448 uint] | bc[9408 int]
    unsigned short* hb  = (unsigned short*)d_ws;
    float* asrc = (float*)(hb + (long)R_REL * N_NODES * HID);
    float* adst = asrc + R_REL * N_NODES * HEADS;
    int*   cnt  = (int*)(adst + R_REL * N_NODES * HEADS);
    unsigned short* wtb = (unsigned short*)(cnt + R_REL * N_NODES);
    unsigned short* slots = wtb + R_REL * HID * HID;
    unsigned* regions = (unsigned*)(slots + (long)R_REL * N_NODES * CAP);
    int* bc = (int*)(regions + (long)R_REL * CHUNKS_A * NPART * CAP_A);

    setup_fillA_kernel<<<SETUP_BLKS + FILLA_BLKS, 256, 0, stream>>>(
        W, gate, edge_idx, wtb, out + (long)N_NODES * HID, regions, bc);
    gemm_fillB_kernel<<<FILLB_BLKS + GEMM_BLKS, 256, 0, stream>>>(
        x, wtb, hb, att_src, att_dst, asrc, adst, regions, bc, cnt, slots);
    aggr_kernel<<<N_NODES / 4, 256, 0, stream>>>(hb, cnt, slots, asrc, adst, gate,
                                                 x, bias, ln_g, ln_b, out);
}